// Round 4
// baseline (123.320 us; speedup 1.0000x reference)
//
#include <hip/hip_runtime.h>
#include <hip/hip_bf16.h>

// SimCLR loss, N=8192, D=128, T=0.1.
//  k1 (prep):  row L2-normalize fp32 -> bf16 znb (unscaled) + znbs (x 10*log2e);
//              selfe[i] = exp2(sum bf16(s*a)*bf16(a)) matching the MFMA diagonal;
//              poslog[i] = 10 * normalized fp32 dot(z_i, z_{i^4096}) (= log pos).
//  k2 (sim):   rowsum of exp2(mfma(znbs_i, znb_j)) over ALL j, no masking.
//              256x256 tile / block, 4 waves x 64 rows; B staged via
//              global_load_lds (linear dest + inverse-swizzled SOURCE, m173),
//              2x16KB double buffer, one barrier per 64-col chunk (T3 minimum).
//  k3a/k3b:    denom = sum(partials) - selfe; loss = mean(log(denom) - poslog).
//
// Round-3 lesson: reg-staging array st[8] spilled (VGPR capped 84, WRITE_SIZE
// 88 MB of scratch traffic, 54 us latency-bound). global_load_lds removes the
// staging registers entirely; 256x256 tile halves LDS read redundancy.

constexpr int N = 8192;
constexpr int D = 128;
constexpr float SCALE = 14.4269504088896341f;  // 10 * log2(e)

typedef short bf16x8 __attribute__((ext_vector_type(8)));
typedef float f32x4 __attribute__((ext_vector_type(4)));

#if __has_builtin(__builtin_amdgcn_exp2f)
#define EXP2(x) __builtin_amdgcn_exp2f(x)
#else
#define EXP2(x) exp2f(x)
#endif

static __device__ __forceinline__ unsigned short f2bf(float x) {
  __hip_bfloat16 h = __float2bfloat16(x);  // RTNE
  unsigned short u;
  __builtin_memcpy(&u, &h, 2);
  return u;
}
static __device__ __forceinline__ float bf2f(unsigned short u) {
  unsigned int x = ((unsigned int)u) << 16;
  float f;
  __builtin_memcpy(&f, &x, 4);
  return f;
}
static __device__ __forceinline__ void gload_lds16(const void* g, void* l) {
  __builtin_amdgcn_global_load_lds(
      (const __attribute__((address_space(1))) unsigned int*)g,
      (__attribute__((address_space(3))) unsigned int*)l, 16, 0, 0);
}

// ------------- kernel 1: normalize + bf16 convert + self-term + pos-term -------------
__global__ __launch_bounds__(256) void simclr_prep(const float* __restrict__ z,
                                                   unsigned short* __restrict__ znb,
                                                   unsigned short* __restrict__ znbs,
                                                   float* __restrict__ selfe,
                                                   float* __restrict__ poslog) {
  const int row = blockIdx.x * 4 + (threadIdx.x >> 6);
  const int par = row ^ (N / 2);
  const int lane = threadIdx.x & 63;
  const float2 v = *(const float2*)(z + row * D + lane * 2);
  const float2 b = *(const float2*)(z + par * D + lane * 2);
  float ss = v.x * v.x + v.y * v.y;
  float sb = b.x * b.x + b.y * b.y;
  float dp = v.x * b.x + v.y * b.y;
#pragma unroll
  for (int m = 1; m < 64; m <<= 1) {
    ss += __shfl_xor(ss, m);
    sb += __shfl_xor(sb, m);
    dp += __shfl_xor(dp, m);
  }
  const float rn = rsqrtf(ss);
  const float a0 = v.x * rn, a1 = v.y * rn;
  const unsigned short u0 = f2bf(a0), u1 = f2bf(a1);
  const unsigned short s0 = f2bf(a0 * SCALE), s1 = f2bf(a1 * SCALE);
  *(unsigned int*)(znb + row * D + lane * 2) = (unsigned int)u0 | ((unsigned int)u1 << 16);
  *(unsigned int*)(znbs + row * D + lane * 2) = (unsigned int)s0 | ((unsigned int)s1 << 16);
  // self dot with exactly the MFMA's bf16 products (fp32 sum; order-only mismatch ~1e-5)
  float sa = bf2f(s0) * bf2f(u0) + bf2f(s1) * bf2f(u1);
#pragma unroll
  for (int m = 1; m < 64; m <<= 1) sa += __shfl_xor(sa, m);
  if (lane == 0) {
    selfe[row] = EXP2(sa);
    poslog[row] = 10.0f * dp * rsqrtf(ss * sb);
  }
}

// ---------------- kernel 2: similarity row-sums (mask-free) ----------------
// grid = (N/256)*(N/256) = 1024 blocks; block = 256 threads (4 waves).
// Block: 256 rows x 256 cols; wave w owns rows [RB + w*64, +64).
// B-cols staged in 64-row chunks (16KB), double-buffered.
__global__ __launch_bounds__(256, 3) void simclr_sim(const unsigned short* __restrict__ znb,
                                                     const unsigned short* __restrict__ znbs,
                                                     float* __restrict__ partials) {
  __shared__ unsigned short lb[2][64 * 128];  // 2 x 16KB, row = 256B, XOR-swizzled

  const int bi = blockIdx.x;
  const int RB = (bi >> 5) << 8;   // row-block base (x256)
  const int CB = (bi & 31) << 8;   // col-block base (x256)
  const int tid = threadIdx.x;
  const int lane = tid & 63;
  const int w = tid >> 6;
  const int l15 = lane & 15, l4 = lane >> 4;

  // A fragments (pre-scaled by 10*log2e): 4 row-tiles x 4 K-steps, 64 VGPRs.
  // A layout (16x16x32): lane holds A[l&15][(l>>4)*8 + 0..7], k = s*32 + l4*8.
  bf16x8 afrag[4][4];
#pragma unroll
  for (int rt = 0; rt < 4; ++rt)
#pragma unroll
    for (int s = 0; s < 4; ++s)
      afrag[rt][s] =
          *(const bf16x8*)(znbs + (RB + w * 64 + rt * 16 + l15) * D + s * 32 + l4 * 8);

  float dpart[16];
#pragma unroll
  for (int k = 0; k < 16; ++k) dpart[k] = 0.f;

  // Stage chunk cc (64 B-rows = 16KB) into lb[buf]: wave w, instr i covers
  // LDS [ (w*4+i)*1024, +1024 ) = B-rows 4*(w*4+i)..+3. Linear dest; source
  // chunk pre-swizzled: position sl holds global chunk sl ^ (rr&7).
#define STAGE(buf_, cc_)                                                        \
  {                                                                             \
    _Pragma("unroll") for (int i = 0; i < 4; ++i) {                             \
      const int rr = (w * 4 + i) * 4 + l4;                                      \
      const unsigned short* g =                                                 \
          znb + (CB + (cc_) * 64 + rr) * D + ((l15 ^ (rr & 7)) << 3);           \
      gload_lds16(g, (char*)lb[buf_] + (w * 4 + i) * 1024);                     \
    }                                                                           \
  }

  STAGE(0, 0);
  __syncthreads();  // drains vmcnt(0): chunk 0 visible

  int buf = 0;
  for (int cc = 0; cc < 4; ++cc) {
    if (cc < 3) STAGE(buf ^ 1, cc + 1);  // prefetch next chunk into other buffer
    const char* lbc = (const char*)lb[buf];
#pragma unroll
    for (int jt = 0; jt < 4; ++jt) {
      const int jr = jt * 16 + l15;  // B-row within chunk
      const int swz = (jr & 7) << 4;
      // B layout: lane holds B[s*32 + l4*8 + 0..7][l15]
      bf16x8 bfrag[4];
#pragma unroll
      for (int s = 0; s < 4; ++s)
        bfrag[s] = *(const bf16x8*)(lbc + jr * 256 + ((s * 64 + l4 * 16) ^ swz));
      f32x4 acc[4];
#pragma unroll
      for (int rt = 0; rt < 4; ++rt) acc[rt] = f32x4{0.f, 0.f, 0.f, 0.f};
#pragma unroll
      for (int s = 0; s < 4; ++s)
#pragma unroll
        for (int rt = 0; rt < 4; ++rt)
          acc[rt] = __builtin_amdgcn_mfma_f32_16x16x32_bf16(afrag[rt][s], bfrag[s],
                                                            acc[rt], 0, 0, 0);
      // acc = 10*log2(e)*dot (A pre-scaled): exp2 + accumulate
#pragma unroll
      for (int rt = 0; rt < 4; ++rt)
#pragma unroll
        for (int r = 0; r < 4; ++r) dpart[rt * 4 + r] += EXP2(acc[rt][r]);
    }
    __syncthreads();  // vmcnt(0)+lgkmcnt(0)+barrier: next chunk ready, buf reads drained
    buf ^= 1;
  }
#undef STAGE

  // reduce across the 16 column-lanes; lanes with l15==0 hold full row sums
#pragma unroll
  for (int m = 1; m < 16; m <<= 1)
#pragma unroll
    for (int k = 0; k < 16; ++k) dpart[k] += __shfl_xor(dpart[k], m);

  if (l15 == 0) {
    // C/D layout: row = l4*4 + r within each 16-row tile
    float* pp = partials + (bi & 31) * N + RB + w * 64 + l4 * 4;
#pragma unroll
    for (int rt = 0; rt < 4; ++rt)
#pragma unroll
      for (int r = 0; r < 4; ++r) pp[rt * 16 + r] = dpart[rt * 4 + r];
  }
}

// ---------------- kernel 3a: per-row loss, per-block partial sums ----------------
__global__ __launch_bounds__(256) void simclr_rowloss(const float* __restrict__ partials,
                                                      const float* __restrict__ selfe,
                                                      const float* __restrict__ poslog,
                                                      float* __restrict__ bsum) {
  const int tid = threadIdx.x;
  const int i = blockIdx.x * 256 + tid;
  float d = -selfe[i];
#pragma unroll
  for (int cb = 0; cb < 32; ++cb) d += partials[cb * N + i];
  float s = logf(d) - poslog[i];
#pragma unroll
  for (int m = 1; m < 64; m <<= 1) s += __shfl_xor(s, m);
  __shared__ float acc[4];
  if ((tid & 63) == 0) acc[tid >> 6] = s;
  __syncthreads();
  if (tid == 0) bsum[blockIdx.x] = acc[0] + acc[1] + acc[2] + acc[3];
}

// ---------------- kernel 3b: final scalar ----------------
__global__ __launch_bounds__(64) void simclr_final(const float* __restrict__ bsum,
                                                   float* __restrict__ out) {
  const int tid = threadIdx.x;
  float s = (tid < 32) ? bsum[tid] : 0.f;
#pragma unroll
  for (int m = 1; m < 64; m <<= 1) s += __shfl_xor(s, m);
  if (tid == 0) out[0] = s * (1.0f / N);
}

extern "C" void kernel_launch(void* const* d_in, const int* in_sizes, int n_in,
                              void* d_out, int out_size, void* d_ws, size_t ws_size,
                              hipStream_t stream) {
  const float* z = (const float*)d_in[0];
  float* out = (float*)d_out;

  float* partials = (float*)d_ws;                      // 32*N
  float* selfe = partials + 32 * N;                    // N
  float* poslog = selfe + N;                           // N
  float* bsum = poslog + N;                            // 32 (pad to 64)
  unsigned short* znb = (unsigned short*)(bsum + 64);  // N*D bf16 (16B-aligned)
  unsigned short* znbs = znb + N * D;                  // N*D bf16

  simclr_prep<<<N / 4, 256, 0, stream>>>(z, znb, znbs, selfe, poslog);
  simclr_sim<<<(N / 256) * (N / 256), 256, 0, stream>>>(znb, znbs, partials);
  simclr_rowloss<<<N / 256, 256, 0, stream>>>(partials, selfe, poslog, bsum);
  simclr_final<<<1, 64, 0, stream>>>(bsum, out);
}

// Round 7
// 104.414 us; speedup vs baseline: 1.1811x; 1.1811x over previous
//
#include <hip/hip_runtime.h>
#include <hip/hip_bf16.h>

// SimCLR loss, N=8192, D=128, T=0.1.
//  k1 (prep):  row L2-normalize fp32 -> bf16 znb (unscaled) + znbs (x 10*log2e);
//              selfe[i] = exp2(MFMA-matched self dot); poslog[i] = 10*fp32 dot.
//  k2 (simA/simB): rowsum of exp2(mfma(znbs_i, znb_j)) over ALL j, no masking.
//              WITHIN-BENCH A/B (round-6: 3rd acquisition timeout; maximize info
//              per successful bench):
//              simA rows 0..4095:  4-wave block, demand ~132, waves_per_eu(3,3).
//              simB rows 4096..8191: 8-wave/512-thr block, demand ~90, (4,4).
//              Both: 256x256 tile, global_load_lds (linear dest + inverse-
//              swizzled source), 2x16KB double buffer, 1 barrier/chunk.
//              Per-dispatch VGPR_Count/WRITE_SIZE/dur decide round 7.
//  k3a/k3b:    denom = sum(partials) - selfe; loss = mean(log(denom) - poslog).
//
// Round-4 diagnosis under test: VGPR_Count=84 (=512/6) twice -> occupancy
// heuristic targets 6 waves/SIMD and spills ~100 regs/thread (spill-stores ==
// ~100MB WRITE_SIZE; spill-fills == MfmaUtil 9%).

constexpr int N = 8192;
constexpr int D = 128;
constexpr float SCALE = 14.4269504088896341f;  // 10 * log2(e)

typedef short bf16x8 __attribute__((ext_vector_type(8)));
typedef float f32x4 __attribute__((ext_vector_type(4)));

#if __has_builtin(__builtin_amdgcn_exp2f)
#define EXP2(x) __builtin_amdgcn_exp2f(x)
#else
#define EXP2(x) exp2f(x)
#endif

static __device__ __forceinline__ unsigned short f2bf(float x) {
  __hip_bfloat16 h = __float2bfloat16(x);  // RTNE
  unsigned short u;
  __builtin_memcpy(&u, &h, 2);
  return u;
}
static __device__ __forceinline__ float bf2f(unsigned short u) {
  unsigned int x = ((unsigned int)u) << 16;
  float f;
  __builtin_memcpy(&f, &x, 4);
  return f;
}
static __device__ __forceinline__ void gload_lds16(const void* g, void* l) {
  __builtin_amdgcn_global_load_lds(
      (const __attribute__((address_space(1))) unsigned int*)g,
      (__attribute__((address_space(3))) unsigned int*)l, 16, 0, 0);
}

// ------------- kernel 1: normalize + bf16 convert + self-term + pos-term -------------
__global__ __launch_bounds__(256) void simclr_prep(const float* __restrict__ z,
                                                   unsigned short* __restrict__ znb,
                                                   unsigned short* __restrict__ znbs,
                                                   float* __restrict__ selfe,
                                                   float* __restrict__ poslog) {
  const int row = blockIdx.x * 4 + (threadIdx.x >> 6);
  const int par = row ^ (N / 2);
  const int lane = threadIdx.x & 63;
  const float2 v = *(const float2*)(z + row * D + lane * 2);
  const float2 b = *(const float2*)(z + par * D + lane * 2);
  float ss = v.x * v.x + v.y * v.y;
  float sb = b.x * b.x + b.y * b.y;
  float dp = v.x * b.x + v.y * b.y;
#pragma unroll
  for (int m = 1; m < 64; m <<= 1) {
    ss += __shfl_xor(ss, m);
    sb += __shfl_xor(sb, m);
    dp += __shfl_xor(dp, m);
  }
  const float rn = rsqrtf(ss);
  const float a0 = v.x * rn, a1 = v.y * rn;
  const unsigned short u0 = f2bf(a0), u1 = f2bf(a1);
  const unsigned short s0 = f2bf(a0 * SCALE), s1 = f2bf(a1 * SCALE);
  *(unsigned int*)(znb + row * D + lane * 2) = (unsigned int)u0 | ((unsigned int)u1 << 16);
  *(unsigned int*)(znbs + row * D + lane * 2) = (unsigned int)s0 | ((unsigned int)s1 << 16);
  // self dot with exactly the MFMA's bf16 products (fp32 sum; order-only mismatch ~1e-5)
  float sa = bf2f(s0) * bf2f(u0) + bf2f(s1) * bf2f(u1);
#pragma unroll
  for (int m = 1; m < 64; m <<= 1) sa += __shfl_xor(sa, m);
  if (lane == 0) {
    selfe[row] = EXP2(sa);
    poslog[row] = 10.0f * dp * rsqrtf(ss * sb);
  }
}

// ---------------- kernel 2A: sim rows [0,4096), 4 waves, waves_per_eu(3,3) ----------------
// grid = 16*32 = 512 blocks; block = 256 threads. Wave w owns rows [RB+w*64, +64).
__global__ __launch_bounds__(256)
__attribute__((amdgpu_waves_per_eu(3, 3)))
void simclr_simA(const unsigned short* __restrict__ znb,
                 const unsigned short* __restrict__ znbs,
                 float* __restrict__ partials) {
  __shared__ unsigned short lb[2][64 * 128];  // 2 x 16KB, row = 256B, XOR-swizzled

  const int bi = blockIdx.x;
  const int RB = (bi >> 5) << 8;   // row-block base in [0, 4096)
  const int CB = (bi & 31) << 8;   // col-block base (x256)
  const int tid = threadIdx.x;
  const int lane = tid & 63;
  const int w = tid >> 6;
  const int l15 = lane & 15, l4 = lane >> 4;

  // A layout (16x16x32): lane holds A[l&15][(l>>4)*8 + 0..7], k = s*32 + l4*8.
  bf16x8 afrag[4][4];
#pragma unroll
  for (int rt = 0; rt < 4; ++rt)
#pragma unroll
    for (int s = 0; s < 4; ++s)
      afrag[rt][s] =
          *(const bf16x8*)(znbs + (RB + w * 64 + rt * 16 + l15) * D + s * 32 + l4 * 8);

  float dpart[16];
#pragma unroll
  for (int k = 0; k < 16; ++k) dpart[k] = 0.f;

  // Stage chunk cc (64 B-rows = 16KB): linear dest, inverse-swizzled source.
#define STAGE_A(buf_, cc_)                                                      \
  {                                                                             \
    _Pragma("unroll") for (int i = 0; i < 4; ++i) {                             \
      const int rr = (w * 4 + i) * 4 + l4;                                      \
      const unsigned short* g =                                                 \
          znb + (CB + (cc_) * 64 + rr) * D + ((l15 ^ (rr & 7)) << 3);           \
      gload_lds16(g, (char*)lb[buf_] + (w * 4 + i) * 1024);                     \
    }                                                                           \
  }

  STAGE_A(0, 0);
  __syncthreads();

  int buf = 0;
  for (int cc = 0; cc < 4; ++cc) {
    if (cc < 3) STAGE_A(buf ^ 1, cc + 1);
    const char* lbc = (const char*)lb[buf];
#pragma unroll
    for (int jt = 0; jt < 4; ++jt) {
      const int jr = jt * 16 + l15;
      const int swz = (jr & 7) << 4;
      bf16x8 bfrag[4];
#pragma unroll
      for (int s = 0; s < 4; ++s)
        bfrag[s] = *(const bf16x8*)(lbc + jr * 256 + ((s * 64 + l4 * 16) ^ swz));
      f32x4 acc[4];
#pragma unroll
      for (int rt = 0; rt < 4; ++rt) acc[rt] = f32x4{0.f, 0.f, 0.f, 0.f};
#pragma unroll
      for (int s = 0; s < 4; ++s)
#pragma unroll
        for (int rt = 0; rt < 4; ++rt)
          acc[rt] = __builtin_amdgcn_mfma_f32_16x16x32_bf16(afrag[rt][s], bfrag[s],
                                                            acc[rt], 0, 0, 0);
#pragma unroll
      for (int rt = 0; rt < 4; ++rt)
#pragma unroll
        for (int r = 0; r < 4; ++r) dpart[rt * 4 + r] += EXP2(acc[rt][r]);
    }
    __syncthreads();
    buf ^= 1;
  }
#undef STAGE_A

#pragma unroll
  for (int m = 1; m < 16; m <<= 1)
#pragma unroll
    for (int k = 0; k < 16; ++k) dpart[k] += __shfl_xor(dpart[k], m);

  if (l15 == 0) {
    float* pp = partials + (bi & 31) * N + RB + w * 64 + l4 * 4;
#pragma unroll
    for (int rt = 0; rt < 4; ++rt)
#pragma unroll
      for (int r = 0; r < 4; ++r) pp[rt * 16 + r] = dpart[rt * 4 + r];
  }
}

// ---------------- kernel 2B: sim rows [4096,8192), 8 waves, low pressure ----------------
// grid = 16*32 = 512 blocks; block = 512 threads. Wave w owns rows [RB+w*32, +32).
// afrag 32 VGPR, demand ~90: fits even a heuristic-chosen 6-wave budget closely.
__global__ __launch_bounds__(512)
__attribute__((amdgpu_waves_per_eu(4, 4)))
void simclr_simB(const unsigned short* __restrict__ znb,
                 const unsigned short* __restrict__ znbs,
                 float* __restrict__ partials) {
  __shared__ unsigned short lb[2][64 * 128];  // 2 x 16KB, row = 256B, XOR-swizzled

  const int bi = blockIdx.x;
  const int RB = 4096 + ((bi >> 5) << 8);  // row-block base in [4096, 8192)
  const int CB = (bi & 31) << 8;           // col-block base (x256)
  const int tid = threadIdx.x;
  const int lane = tid & 63;
  const int w = tid >> 6;  // 0..7
  const int l15 = lane & 15, l4 = lane >> 4;

  bf16x8 afrag[2][4];
#pragma unroll
  for (int rt = 0; rt < 2; ++rt)
#pragma unroll
    for (int s = 0; s < 4; ++s)
      afrag[rt][s] =
          *(const bf16x8*)(znbs + (RB + w * 32 + rt * 16 + l15) * D + s * 32 + l4 * 8);

  float dpart[8];
#pragma unroll
  for (int k = 0; k < 8; ++k) dpart[k] = 0.f;

  // 8 waves x 2 instrs cover the 16KB chunk.
#define STAGE_B(buf_, cc_)                                                      \
  {                                                                             \
    _Pragma("unroll") for (int i = 0; i < 2; ++i) {                             \
      const int rr = (w * 2 + i) * 4 + l4;                                      \
      const unsigned short* g =                                                 \
          znb + (CB + (cc_) * 64 + rr) * D + ((l15 ^ (rr & 7)) << 3);           \
      gload_lds16(g, (char*)lb[buf_] + (w * 2 + i) * 1024);                     \
    }                                                                           \
  }

  STAGE_B(0, 0);
  __syncthreads();

  int buf = 0;
  for (int cc = 0; cc < 4; ++cc) {
    if (cc < 3) STAGE_B(buf ^ 1, cc + 1);
    const char* lbc = (const char*)lb[buf];
#pragma unroll
    for (int jt = 0; jt < 4; ++jt) {
      const int jr = jt * 16 + l15;
      const int swz = (jr & 7) << 4;
      bf16x8 bfrag[4];
#pragma unroll
      for (int s = 0; s < 4; ++s)
        bfrag[s] = *(const bf16x8*)(lbc + jr * 256 + ((s * 64 + l4 * 16) ^ swz));
      f32x4 acc[2];
#pragma unroll
      for (int rt = 0; rt < 2; ++rt) acc[rt] = f32x4{0.f, 0.f, 0.f, 0.f};
#pragma unroll
      for (int s = 0; s < 4; ++s)
#pragma unroll
        for (int rt = 0; rt < 2; ++rt)
          acc[rt] = __builtin_amdgcn_mfma_f32_16x16x32_bf16(afrag[rt][s], bfrag[s],
                                                            acc[rt], 0, 0, 0);
#pragma unroll
      for (int rt = 0; rt < 2; ++rt)
#pragma unroll
        for (int r = 0; r < 4; ++r) dpart[rt * 4 + r] += EXP2(acc[rt][r]);
    }
    __syncthreads();
    buf ^= 1;
  }
#undef STAGE_B

#pragma unroll
  for (int m = 1; m < 16; m <<= 1)
#pragma unroll
    for (int k = 0; k < 8; ++k) dpart[k] += __shfl_xor(dpart[k], m);

  if (l15 == 0) {
    float* pp = partials + (bi & 31) * N + RB + w * 32 + l4 * 4;
#pragma unroll
    for (int rt = 0; rt < 2; ++rt)
#pragma unroll
      for (int r = 0; r < 4; ++r) pp[rt * 16 + r] = dpart[rt * 4 + r];
  }
}

// ---------------- kernel 3a: per-row loss, per-block partial sums ----------------
__global__ __launch_bounds__(256) void simclr_rowloss(const float* __restrict__ partials,
                                                      const float* __restrict__ selfe,
                                                      const float* __restrict__ poslog,
                                                      float* __restrict__ bsum) {
  const int tid = threadIdx.x;
  const int i = blockIdx.x * 256 + tid;
  float d = -selfe[i];
#pragma unroll
  for (int cb = 0; cb < 32; ++cb) d += partials[cb * N + i];
  float s = logf(d) - poslog[i];
#pragma unroll
  for (int m = 1; m < 64; m <<= 1) s += __shfl_xor(s, m);
  __shared__ float acc[4];
  if ((tid & 63) == 0) acc[tid >> 6] = s;
  __syncthreads();
  if (tid == 0) bsum[blockIdx.x] = acc[0] + acc[1] + acc[2] + acc[3];
}

// ---------------- kernel 3b: final scalar ----------------
__global__ __launch_bounds__(64) void simclr_final(const float* __restrict__ bsum,
                                                   float* __restrict__ out) {
  const int tid = threadIdx.x;
  float s = (tid < 32) ? bsum[tid] : 0.f;
#pragma unroll
  for (int m = 1; m < 64; m <<= 1) s += __shfl_xor(s, m);
  if (tid == 0) out[0] = s * (1.0f / N);
}

extern "C" void kernel_launch(void* const* d_in, const int* in_sizes, int n_in,
                              void* d_out, int out_size, void* d_ws, size_t ws_size,
                              hipStream_t stream) {
  const float* z = (const float*)d_in[0];
  float* out = (float*)d_out;

  float* partials = (float*)d_ws;                      // 32*N
  float* selfe = partials + 32 * N;                    // N
  float* poslog = selfe + N;                           // N
  float* bsum = poslog + N;                            // 32 (pad to 64)
  unsigned short* znb = (unsigned short*)(bsum + 64);  // N*D bf16 (16B-aligned)
  unsigned short* znbs = znb + N * D;                  // N*D bf16

  simclr_prep<<<N / 4, 256, 0, stream>>>(z, znb, znbs, selfe, poslog);
  simclr_simA<<<16 * 32, 256, 0, stream>>>(znb, znbs, partials);
  simclr_simB<<<16 * 32, 512, 0, stream>>>(znb, znbs, partials);
  simclr_rowloss<<<N / 256, 256, 0, stream>>>(partials, selfe, poslog, bsum);
  simclr_final<<<1, 64, 0, stream>>>(bsum, out);
}

// Round 8
// 86.089 us; speedup vs baseline: 1.4325x; 1.2129x over previous
//
#include <hip/hip_runtime.h>
#include <hip/hip_bf16.h>

// SimCLR loss, N=8192, D=128, T=0.1.
//  k1 (prep):  row L2-normalize fp32 -> bf16 znb (unscaled) + znbs (x 10*log2e);
//              selfe[i] = exp2(MFMA-matched self dot); poslog[i] = 10*fp32 dot.
//  k2 (sim):   rowsum of exp2(mfma(znbs_i, znb_j)) over ALL j, no masking.
//              Full grid on the ROUND-7 A/B WINNER (simB structure): 8 waves x
//              512 threads, 256x256 tile, 32 rows/wave, afrag 32 VGPRs, peak
//              demand ~80 <= the allocator's observed 84-reg budget -> no
//              spills (simA's demand-132 variant spilled 104 KB/block and ran
//              4.5x slower per row; waves_per_eu didn't raise the budget).
//  k3a/k3b:    denom = sum(partials) - selfe; loss = mean(log(denom) - poslog).
//
// NOTE: ~44 us of every timed window is the harness's 256 MB d_ws poison fill
// draining on the stream (fillBufferAligned dispatches) — fixed overhead we
// cannot remove; kernel-side budget is what we optimize.

constexpr int N = 8192;
constexpr int D = 128;
constexpr float SCALE = 14.4269504088896341f;  // 10 * log2(e)

typedef short bf16x8 __attribute__((ext_vector_type(8)));
typedef float f32x4 __attribute__((ext_vector_type(4)));

#if __has_builtin(__builtin_amdgcn_exp2f)
#define EXP2(x) __builtin_amdgcn_exp2f(x)
#else
#define EXP2(x) exp2f(x)
#endif

static __device__ __forceinline__ unsigned short f2bf(float x) {
  __hip_bfloat16 h = __float2bfloat16(x);  // RTNE
  unsigned short u;
  __builtin_memcpy(&u, &h, 2);
  return u;
}
static __device__ __forceinline__ float bf2f(unsigned short u) {
  unsigned int x = ((unsigned int)u) << 16;
  float f;
  __builtin_memcpy(&f, &x, 4);
  return f;
}
static __device__ __forceinline__ void gload_lds16(const void* g, void* l) {
  __builtin_amdgcn_global_load_lds(
      (const __attribute__((address_space(1))) unsigned int*)g,
      (__attribute__((address_space(3))) unsigned int*)l, 16, 0, 0);
}

// ------------- kernel 1: normalize + bf16 convert + self-term + pos-term -------------
__global__ __launch_bounds__(256) void simclr_prep(const float* __restrict__ z,
                                                   unsigned short* __restrict__ znb,
                                                   unsigned short* __restrict__ znbs,
                                                   float* __restrict__ selfe,
                                                   float* __restrict__ poslog) {
  const int row = blockIdx.x * 4 + (threadIdx.x >> 6);
  const int par = row ^ (N / 2);
  const int lane = threadIdx.x & 63;
  const float2 v = *(const float2*)(z + row * D + lane * 2);
  const float2 b = *(const float2*)(z + par * D + lane * 2);
  float ss = v.x * v.x + v.y * v.y;
  float sb = b.x * b.x + b.y * b.y;
  float dp = v.x * b.x + v.y * b.y;
#pragma unroll
  for (int m = 1; m < 64; m <<= 1) {
    ss += __shfl_xor(ss, m);
    sb += __shfl_xor(sb, m);
    dp += __shfl_xor(dp, m);
  }
  const float rn = rsqrtf(ss);
  const float a0 = v.x * rn, a1 = v.y * rn;
  const unsigned short u0 = f2bf(a0), u1 = f2bf(a1);
  const unsigned short s0 = f2bf(a0 * SCALE), s1 = f2bf(a1 * SCALE);
  *(unsigned int*)(znb + row * D + lane * 2) = (unsigned int)u0 | ((unsigned int)u1 << 16);
  *(unsigned int*)(znbs + row * D + lane * 2) = (unsigned int)s0 | ((unsigned int)s1 << 16);
  // self dot with exactly the MFMA's bf16 products (fp32 sum; order-only mismatch ~1e-5)
  float sa = bf2f(s0) * bf2f(u0) + bf2f(s1) * bf2f(u1);
#pragma unroll
  for (int m = 1; m < 64; m <<= 1) sa += __shfl_xor(sa, m);
  if (lane == 0) {
    selfe[row] = EXP2(sa);
    poslog[row] = 10.0f * dp * rsqrtf(ss * sb);
  }
}

// ---------------- kernel 2: sim, full grid, 8-wave low-pressure structure ----------------
// grid = (N/256)*(N/256) = 1024 blocks; block = 512 threads (8 waves).
// Wave w owns rows [RB + w*32, +32). B staged via global_load_lds (linear dest,
// inverse-swizzled source), 2x16KB double buffer, 1 barrier per 64-col chunk.
__global__ __launch_bounds__(512)
__attribute__((amdgpu_waves_per_eu(4, 4)))
void simclr_sim(const unsigned short* __restrict__ znb,
                const unsigned short* __restrict__ znbs,
                float* __restrict__ partials) {
  __shared__ unsigned short lb[2][64 * 128];  // 2 x 16KB, row = 256B, XOR-swizzled

  const int bi = blockIdx.x;
  const int RB = (bi >> 5) << 8;   // row-block base (x256)
  const int CB = (bi & 31) << 8;   // col-block base (x256)
  const int tid = threadIdx.x;
  const int lane = tid & 63;
  const int w = tid >> 6;  // 0..7
  const int l15 = lane & 15, l4 = lane >> 4;

  // A layout (16x16x32): lane holds A[l&15][(l>>4)*8 + 0..7], k = s*32 + l4*8.
  bf16x8 afrag[2][4];
#pragma unroll
  for (int rt = 0; rt < 2; ++rt)
#pragma unroll
    for (int s = 0; s < 4; ++s)
      afrag[rt][s] =
          *(const bf16x8*)(znbs + (RB + w * 32 + rt * 16 + l15) * D + s * 32 + l4 * 8);

  float dpart[8];
#pragma unroll
  for (int k = 0; k < 8; ++k) dpart[k] = 0.f;

  // Stage chunk cc (64 B-rows = 16KB): 8 waves x 2 instrs, linear LDS dest,
  // inverse-swizzled global source (position sl holds global chunk sl^(rr&7)).
#define STAGE(buf_, cc_)                                                        \
  {                                                                             \
    _Pragma("unroll") for (int i = 0; i < 2; ++i) {                             \
      const int rr = (w * 2 + i) * 4 + l4;                                      \
      const unsigned short* g =                                                 \
          znb + (CB + (cc_) * 64 + rr) * D + ((l15 ^ (rr & 7)) << 3);           \
      gload_lds16(g, (char*)lb[buf_] + (w * 2 + i) * 1024);                     \
    }                                                                           \
  }

  STAGE(0, 0);
  __syncthreads();

  int buf = 0;
  for (int cc = 0; cc < 4; ++cc) {
    if (cc < 3) STAGE(buf ^ 1, cc + 1);
    const char* lbc = (const char*)lb[buf];
#pragma unroll
    for (int jt = 0; jt < 4; ++jt) {
      const int jr = jt * 16 + l15;
      const int swz = (jr & 7) << 4;
      // B layout: lane holds B[s*32 + l4*8 + 0..7][l15]
      bf16x8 bfrag[4];
#pragma unroll
      for (int s = 0; s < 4; ++s)
        bfrag[s] = *(const bf16x8*)(lbc + jr * 256 + ((s * 64 + l4 * 16) ^ swz));
      f32x4 acc[2];
#pragma unroll
      for (int rt = 0; rt < 2; ++rt) acc[rt] = f32x4{0.f, 0.f, 0.f, 0.f};
#pragma unroll
      for (int s = 0; s < 4; ++s)
#pragma unroll
        for (int rt = 0; rt < 2; ++rt)
          acc[rt] = __builtin_amdgcn_mfma_f32_16x16x32_bf16(afrag[rt][s], bfrag[s],
                                                            acc[rt], 0, 0, 0);
      // acc = 10*log2(e)*dot (A pre-scaled): exp2 + accumulate
#pragma unroll
      for (int rt = 0; rt < 2; ++rt)
#pragma unroll
        for (int r = 0; r < 4; ++r) dpart[rt * 4 + r] += EXP2(acc[rt][r]);
    }
    __syncthreads();
    buf ^= 1;
  }
#undef STAGE

  // reduce across the 16 column-lanes; lanes with l15==0 hold full row sums
#pragma unroll
  for (int m = 1; m < 16; m <<= 1)
#pragma unroll
    for (int k = 0; k < 8; ++k) dpart[k] += __shfl_xor(dpart[k], m);

  if (l15 == 0) {
    // C/D layout: row = l4*4 + r within each 16-row tile
    float* pp = partials + (bi & 31) * N + RB + w * 32 + l4 * 4;
#pragma unroll
    for (int rt = 0; rt < 2; ++rt)
#pragma unroll
      for (int r = 0; r < 4; ++r) pp[rt * 16 + r] = dpart[rt * 4 + r];
  }
}

// ---------------- kernel 3a: per-row loss, per-block partial sums ----------------
__global__ __launch_bounds__(256) void simclr_rowloss(const float* __restrict__ partials,
                                                      const float* __restrict__ selfe,
                                                      const float* __restrict__ poslog,
                                                      float* __restrict__ bsum) {
  const int tid = threadIdx.x;
  const int i = blockIdx.x * 256 + tid;
  float d = -selfe[i];
#pragma unroll
  for (int cb = 0; cb < 32; ++cb) d += partials[cb * N + i];
  float s = logf(d) - poslog[i];
#pragma unroll
  for (int m = 1; m < 64; m <<= 1) s += __shfl_xor(s, m);
  __shared__ float acc[4];
  if ((tid & 63) == 0) acc[tid >> 6] = s;
  __syncthreads();
  if (tid == 0) bsum[blockIdx.x] = acc[0] + acc[1] + acc[2] + acc[3];
}

// ---------------- kernel 3b: final scalar ----------------
__global__ __launch_bounds__(64) void simclr_final(const float* __restrict__ bsum,
                                                   float* __restrict__ out) {
  const int tid = threadIdx.x;
  float s = (tid < 32) ? bsum[tid] : 0.f;
#pragma unroll
  for (int m = 1; m < 64; m <<= 1) s += __shfl_xor(s, m);
  if (tid == 0) out[0] = s * (1.0f / N);
}

extern "C" void kernel_launch(void* const* d_in, const int* in_sizes, int n_in,
                              void* d_out, int out_size, void* d_ws, size_t ws_size,
                              hipStream_t stream) {
  const float* z = (const float*)d_in[0];
  float* out = (float*)d_out;

  float* partials = (float*)d_ws;                      // 32*N
  float* selfe = partials + 32 * N;                    // N
  float* poslog = selfe + N;                           // N
  float* bsum = poslog + N;                            // 32 (pad to 64)
  unsigned short* znb = (unsigned short*)(bsum + 64);  // N*D bf16 (16B-aligned)
  unsigned short* znbs = znb + N * D;                  // N*D bf16

  simclr_prep<<<N / 4, 256, 0, stream>>>(z, znb, znbs, selfe, poslog);
  simclr_sim<<<(N / 256) * (N / 256), 512, 0, stream>>>(znb, znbs, partials);
  simclr_rowloss<<<N / 256, 256, 0, stream>>>(partials, selfe, poslog, bsum);
  simclr_final<<<1, 64, 0, stream>>>(bsum, out);
}